// Round 5
// baseline (133.297 us; speedup 1.0000x reference)
//
#include <hip/hip_runtime.h>

#define B_TOK 2048
#define W_DIM 512
#define E_N 16
#define INTER 1024
#define SH_INTER 2048
#define OUT_DIM 128

typedef unsigned short u16;
typedef unsigned int u32;
typedef __attribute__((ext_vector_type(8))) short bf16x8;
typedef __attribute__((ext_vector_type(4))) float f32x4;

__device__ __forceinline__ u16 f2b(float f) {
    union { float f; unsigned u; } x; x.f = f;
    unsigned r = x.u + 0x7FFFu + ((x.u >> 16) & 1u);
    return (u16)(r >> 16);
}

__device__ __forceinline__ u32 cvtpk(float lo, float hi) {
    u32 r;
    asm("v_cvt_pk_bf16_f32 %0, %1, %2" : "=v"(r) : "v"(lo), "v"(hi));
    return r;
}

__device__ __forceinline__ void gld16(const void* g, void* l) {
    __builtin_amdgcn_global_load_lds(
        (const __attribute__((address_space(1))) void*)g,
        (__attribute__((address_space(3))) void*)l, 16, 0, 0);
}

// meta layout (ints):
// [0..15] counts  [32..47] offs
// [50] n_j1  [51] n_j2
// [64..127] j1e  [128..191] j1m   (g1 jobs, BM=128)
// [192..303] j2e [304..415] j2m   (g2 jobs, BM=64)

// ---------------- fused cast fp32->bf16, block-uniform segment, deep ILP --------
// Unit: group = 8 elems (uint4 out, 2x float4 in). Block tile = 2048 groups.
// All segment group-counts are divisible by 2048 -> segment uniform per block.
struct CastSeg { const float4* src; uint4* dst; int n8; };
struct CastArgs { CastSeg s[8]; };

__global__ __launch_bounds__(256)
void cast_all(CastArgs a) {
    int rem = blockIdx.x * 2048;          // first group of this block
    int s = 0;
    while (rem >= a.s[s].n8) { rem -= a.s[s].n8; ++s; }
    const float4* __restrict__ src = a.s[s].src + (size_t)rem * 2;
    uint4* __restrict__ dst = a.s[s].dst + rem;
    const int t = threadIdx.x;
    float4 v[16];
    #pragma unroll
    for (int k = 0; k < 8; ++k) {
        v[2 * k]     = src[(size_t)(t + k * 256) * 2];
        v[2 * k + 1] = src[(size_t)(t + k * 256) * 2 + 1];
    }
    #pragma unroll
    for (int k = 0; k < 8; ++k) {
        uint4 o;
        o.x = cvtpk(v[2 * k].x,     v[2 * k].y);
        o.y = cvtpk(v[2 * k].z,     v[2 * k].w);
        o.z = cvtpk(v[2 * k + 1].x, v[2 * k + 1].y);
        o.w = cvtpk(v[2 * k + 1].z, v[2 * k + 1].w);
        dst[t + k * 256] = o;
    }
}

// ---------------- gate: fp32 logits, softmax, top-2 (NO atomics) ----------------
__global__ __launch_bounds__(256)
void gate_topk(const float* __restrict__ x, const float* __restrict__ gw,
               int* __restrict__ topi, float* __restrict__ topw) {
    const int lane = threadIdx.x & 63;
    const int wv   = threadIdx.x >> 6;
    const int t    = blockIdx.x * 4 + wv;
    const int e = lane >> 2, q = lane & 3;
    const float4* xr = (const float4*)(x + (size_t)t * W_DIM);
    const float4* wr = (const float4*)(gw + (size_t)e * W_DIM);
    float s = 0.f;
    #pragma unroll
    for (int i = 0; i < W_DIM / 16; ++i) {
        float4 a = xr[q + 4 * i];
        float4 b = wr[q + 4 * i];
        s += a.x * b.x + a.y * b.y + a.z * b.z + a.w * b.w;
    }
    s += __shfl_xor(s, 1);
    s += __shfl_xor(s, 2);
    float sc[16];
    #pragma unroll
    for (int ee = 0; ee < 16; ++ee) sc[ee] = __shfl(s, ee * 4);
    float mx = sc[0];
    #pragma unroll
    for (int ee = 1; ee < 16; ++ee) mx = fmaxf(mx, sc[ee]);
    float p[16]; float sum = 0.f;
    #pragma unroll
    for (int ee = 0; ee < 16; ++ee) { p[ee] = expf(sc[ee] - mx); sum += p[ee]; }
    const float inv = 1.f / sum;
    int i0 = 0; float v0 = sc[0];
    #pragma unroll
    for (int ee = 1; ee < 16; ++ee) if (sc[ee] > v0) { v0 = sc[ee]; i0 = ee; }
    int i1 = -1; float v1 = -1e30f;
    #pragma unroll
    for (int ee = 0; ee < 16; ++ee) if (ee != i0 && sc[ee] > v1) { v1 = sc[ee]; i1 = ee; }
    if (lane == 0) {
        topi[t * 2 + 0] = i0; topi[t * 2 + 1] = i1;
        topw[t * 2 + 0] = p[i0] * inv; topw[t * 2 + 1] = p[i1] * inv;
    }
}

// ---------------- route_build: single block, LDS atomics only ----------------
__global__ __launch_bounds__(256)
void route_build(const int* __restrict__ topi, const float* __restrict__ topw,
                 int* __restrict__ meta, int* __restrict__ glist,
                 float* __restrict__ job_w, int* __restrict__ t2r) {
    __shared__ int cnt[16], cur[16], offs[16];
    const int tid = threadIdx.x;
    if (tid < 16) { cnt[tid] = 0; cur[tid] = 0; }
    __syncthreads();
    for (int i = tid; i < 2 * B_TOK; i += 256) atomicAdd(&cnt[topi[i]], 1);
    __syncthreads();
    if (tid == 0) {
        int acc = 0, jc = 0;
        for (int e = 0; e < 16; ++e) {
            offs[e] = acc; meta[e] = cnt[e]; meta[32 + e] = acc; acc += cnt[e];
        }
        for (int e = 0; e < 16; ++e)
            for (int m = 0; m < cnt[e]; m += 128) { meta[64 + jc] = e; meta[128 + jc] = m; ++jc; }
        for (int m = 0; m < B_TOK; m += 128) { meta[64 + jc] = 16; meta[128 + jc] = m; ++jc; }
        meta[50] = jc;
        jc = 0;
        for (int e = 0; e < 16; ++e)
            for (int m = 0; m < cnt[e]; m += 64) { meta[192 + jc] = e; meta[304 + jc] = m; ++jc; }
        for (int m = 0; m < B_TOK; m += 64) { meta[192 + jc] = 16; meta[304 + jc] = m; ++jc; }
        meta[51] = jc;
    }
    __syncthreads();
    for (int i = tid; i < 2 * B_TOK; i += 256) {
        int e = topi[i];
        int pos = atomicAdd(&cur[e], 1);
        int row = offs[e] + pos;
        glist[row] = i >> 1;
        job_w[row] = topw[i];
        t2r[i] = row;
    }
    for (int t = tid; t < B_TOK; t += 256) glist[4096 + t] = t;
}

// ---------------- G1 merged: dual GEMM + leaky*mul, bf16 gld16, 2-phase dbuf ----
// BM=128 BN=64 BK=32; stage = A 4096 u16 + B1 2048 + B3 2048 = 8192 u16 (16KB), x2
__global__ __launch_bounds__(256)
void g1_dual(const u16* __restrict__ xb, const int* __restrict__ glist, const int* __restrict__ meta,
             const u16* __restrict__ w1b, const u16* __restrict__ w3b,
             const float* __restrict__ b1, const float* __restrict__ b3,
             const u16* __restrict__ sw1b, const u16* __restrict__ sw3b,
             const float* __restrict__ sb1, const float* __restrict__ sb3,
             u16* __restrict__ hbuf, u16* __restrict__ pbuf) {
    const int job = blockIdx.x;
    if (job >= meta[50]) return;
    const int e  = meta[64 + job];
    const int m0 = meta[128 + job];
    const bool sh = (e == 16);
    if (!sh && blockIdx.y >= (INTER / 64)) return;
    const int n0 = blockIdx.y * 64;
    const int N  = sh ? SH_INTER : INTER;
    const u16* B1 = sh ? sw1b : (w1b + (size_t)e * INTER * W_DIM);
    const u16* B3 = sh ? sw3b : (w3b + (size_t)e * INTER * W_DIM);
    const float* bb1 = sh ? sb1 : (b1 + (size_t)e * INTER);
    const float* bb3 = sh ? sb3 : (b3 + (size_t)e * INTER);
    const int abase = sh ? (4096 + m0) : (meta[32 + e] + m0);
    const int Mrows = (sh ? B_TOK : meta[e]) - m0;
    u16* outp = sh ? pbuf : hbuf;
    const int orow0 = sh ? m0 : (meta[32 + e] + m0);

    __shared__ __align__(16) u16 lds[2 * 8192];

    const int tid = threadIdx.x, lane = tid & 63, wv = tid >> 6;
    const int rA0 = tid >> 2, rA1 = rA0 + 64;
    const int kq = (tid & 3) * 8;
    const int tok0 = glist[abase + (rA0 < Mrows ? rA0 : Mrows - 1)];
    const int tok1 = glist[abase + (rA1 < Mrows ? rA1 : Mrows - 1)];
    const u16* gA0 = xb + (size_t)tok0 * W_DIM + kq;
    const u16* gA1 = xb + (size_t)tok1 * W_DIM + kq;
    const u16* gB1 = B1 + (size_t)(n0 + rA0) * W_DIM + kq;
    const u16* gB3 = B3 + (size_t)(n0 + rA0) * W_DIM + kq;

    const int wm = wv >> 1, wn = wv & 1;
    const int l15 = lane & 15, lhi = lane >> 4;

    f32x4 a1[4][2] = {};
    f32x4 a3[4][2] = {};

    auto stage = [&](int s, int k0) {
        u16* b = &lds[s * 8192];
        gld16(gA0 + k0, b + tid * 8);
        gld16(gA1 + k0, b + 2048 + tid * 8);
        gld16(gB1 + k0, b + 4096 + tid * 8);
        gld16(gB3 + k0, b + 6144 + tid * 8);
    };

    const int NT = W_DIM / 32;
    int cur = 0;
    stage(0, 0);
    for (int t = 0; t < NT; ++t) {
        __syncthreads();
        if (t + 1 < NT) stage(cur ^ 1, (t + 1) * 32);
        const u16* bb = &lds[cur * 8192];
        bf16x8 af[4], f1[2], f3[2];
        #pragma unroll
        for (int i = 0; i < 4; ++i)
            af[i] = *(const bf16x8*)&bb[(wm * 64 + i * 16 + l15) * 32 + lhi * 8];
        #pragma unroll
        for (int j = 0; j < 2; ++j) {
            f1[j] = *(const bf16x8*)&bb[4096 + (wn * 32 + j * 16 + l15) * 32 + lhi * 8];
            f3[j] = *(const bf16x8*)&bb[6144 + (wn * 32 + j * 16 + l15) * 32 + lhi * 8];
        }
        #pragma unroll
        for (int i = 0; i < 4; ++i)
            #pragma unroll
            for (int j = 0; j < 2; ++j) {
                a1[i][j] = __builtin_amdgcn_mfma_f32_16x16x32_bf16(af[i], f1[j], a1[i][j], 0, 0, 0);
                a3[i][j] = __builtin_amdgcn_mfma_f32_16x16x32_bf16(af[i], f3[j], a3[i][j], 0, 0, 0);
            }
        cur ^= 1;
    }

    #pragma unroll
    for (int i = 0; i < 4; ++i)
    #pragma unroll
    for (int j = 0; j < 2; ++j) {
        const int col = n0 + wn * 32 + j * 16 + l15;
        const float vb1 = bb1[col];
        const float vb3 = bb3[col];
        #pragma unroll
        for (int r = 0; r < 4; ++r) {
            const int gm = wm * 64 + i * 16 + lhi * 4 + r;
            if (gm < Mrows) {
                float v1 = a1[i][j][r] + vb1;
                float v3 = a3[i][j][r] + vb3;
                v1 = v1 >= 0.f ? v1 : 0.01f * v1;
                outp[(size_t)(orow0 + gm) * N + col] = f2b(v1 * v3);
            }
        }
    }
}

// ---------------- G2 merged: GEMM + bias (+scale), bf16 gld16, fp32 out ----------
// BM=64 BN=64 BK=32; stage = 2048 + 2048 u16 (8KB), x2
__global__ __launch_bounds__(256)
void g2_gemm(const int* __restrict__ meta,
             const u16* __restrict__ hbuf, const u16* __restrict__ pbuf,
             const u16* __restrict__ w2b, const float* __restrict__ b2,
             const u16* __restrict__ sw2b, const float* __restrict__ sb2,
             const float* __restrict__ job_w,
             float* __restrict__ y2, float* __restrict__ zbuf) {
    const int job = blockIdx.x;
    if (job >= meta[51]) return;
    const int e  = meta[192 + job];
    const int m0 = meta[304 + job];
    const bool sh = (e == 16);
    const int n0 = blockIdx.y * 64;
    const int K  = sh ? SH_INTER : INTER;
    const u16* A = sh ? pbuf : hbuf;
    const int Arow0 = sh ? m0 : (meta[32 + e] + m0);
    const u16* Bw = sh ? sw2b : (w2b + (size_t)e * W_DIM * INTER);
    const float* bias = sh ? sb2 : (b2 + (size_t)e * W_DIM);
    const int Mrows = (sh ? B_TOK : meta[e]) - m0;
    const float* scale = sh ? nullptr : (job_w + Arow0);
    float* outp = sh ? zbuf : y2;

    __shared__ __align__(16) u16 lds[2 * 4096];

    const int tid = threadIdx.x, lane = tid & 63, wv = tid >> 6;
    const int rA = tid >> 2;
    const int kq = (tid & 3) * 8;
    const u16* gA = A + (size_t)(Arow0 + (rA < Mrows ? rA : Mrows - 1)) * K + kq;
    const u16* gB = Bw + (size_t)(n0 + rA) * K + kq;

    const int wm = wv >> 1, wn = wv & 1;
    const int l15 = lane & 15, lhi = lane >> 4;

    f32x4 acc[2][2] = {};

    auto stage = [&](int s, int k0) {
        u16* b = &lds[s * 4096];
        gld16(gA + k0, b + tid * 8);
        gld16(gB + k0, b + 2048 + tid * 8);
    };

    const int NT = K / 32;
    int cur = 0;
    stage(0, 0);
    for (int t = 0; t < NT; ++t) {
        __syncthreads();
        if (t + 1 < NT) stage(cur ^ 1, (t + 1) * 32);
        const u16* bb = &lds[cur * 4096];
        bf16x8 af[2], bf[2];
        #pragma unroll
        for (int i = 0; i < 2; ++i)
            af[i] = *(const bf16x8*)&bb[(wm * 32 + i * 16 + l15) * 32 + lhi * 8];
        #pragma unroll
        for (int j = 0; j < 2; ++j)
            bf[j] = *(const bf16x8*)&bb[2048 + (wn * 32 + j * 16 + l15) * 32 + lhi * 8];
        #pragma unroll
        for (int i = 0; i < 2; ++i)
            #pragma unroll
            for (int j = 0; j < 2; ++j)
                acc[i][j] = __builtin_amdgcn_mfma_f32_16x16x32_bf16(af[i], bf[j], acc[i][j], 0, 0, 0);
        cur ^= 1;
    }

    #pragma unroll
    for (int i = 0; i < 2; ++i)
    #pragma unroll
    for (int j = 0; j < 2; ++j) {
        const int col = n0 + wn * 32 + j * 16 + l15;
        const float bb = bias[col];
        #pragma unroll
        for (int r = 0; r < 4; ++r) {
            const int gm = wm * 32 + i * 16 + lhi * 4 + r;
            if (gm < Mrows) {
                float v = acc[i][j][r] + bb;
                if (scale) v *= scale[gm];
                outp[(size_t)(Arow0 + gm) * W_DIM + col] = v;
            }
        }
    }
}

// ---------------- combine: ybf = bf16(y2[r0] + y2[r1] + z) ----------------
__global__ __launch_bounds__(256)
void combine_k(const float* __restrict__ y2, const float* __restrict__ z,
               const int* __restrict__ t2r, u16* __restrict__ ybf) {
    int idx = blockIdx.x * 256 + threadIdx.x;
    int t = idx >> 7;
    int w4 = (idx & 127) << 2;
    int r0 = t2r[t * 2 + 0], r1 = t2r[t * 2 + 1];
    const float4 a = *(const float4*)(y2 + (size_t)r0 * W_DIM + w4);
    const float4 b = *(const float4*)(y2 + (size_t)r1 * W_DIM + w4);
    const float4 c = *(const float4*)(z + (size_t)t * W_DIM + w4);
    ushort4 o;
    o.x = f2b(a.x + b.x + c.x);
    o.y = f2b(a.y + b.y + c.y);
    o.z = f2b(a.z + b.z + c.z);
    o.w = f2b(a.w + b.w + c.w);
    *(ushort4*)(ybf + (size_t)t * W_DIM + w4) = o;
}

// ---------------- output projection: out = ybf @ ow^T + ob ----------------
__global__ __launch_bounds__(256)
void gout(const u16* __restrict__ ybf, const u16* __restrict__ owb,
          const float* __restrict__ ob, float* __restrict__ out) {
    const int m0 = blockIdx.x * 64, n0 = blockIdx.y * 64;
    __shared__ __align__(16) u16 lds[2 * 4096];
    const int tid = threadIdx.x, lane = tid & 63, wv = tid >> 6;
    const int rA = tid >> 2;
    const int kq = (tid & 3) * 8;
    const u16* gA = ybf + (size_t)(m0 + rA) * W_DIM + kq;
    const u16* gB = owb + (size_t)(n0 + rA) * W_DIM + kq;
    const int wm = wv >> 1, wn = wv & 1;
    const int l15 = lane & 15, lhi = lane >> 4;
    f32x4 acc[2][2] = {};
    auto stage = [&](int s, int k0) {
        u16* b = &lds[s * 4096];
        gld16(gA + k0, b + tid * 8);
        gld16(gB + k0, b + 2048 + tid * 8);
    };
    const int NT = W_DIM / 32;
    int cur = 0;
    stage(0, 0);
    for (int t = 0; t < NT; ++t) {
        __syncthreads();
        if (t + 1 < NT) stage(cur ^ 1, (t + 1) * 32);
        const u16* bb = &lds[cur * 4096];
        bf16x8 af[2], bf[2];
        #pragma unroll
        for (int i = 0; i < 2; ++i)
            af[i] = *(const bf16x8*)&bb[(wm * 32 + i * 16 + l15) * 32 + lhi * 8];
        #pragma unroll
        for (int j = 0; j < 2; ++j)
            bf[j] = *(const bf16x8*)&bb[2048 + (wn * 32 + j * 16 + l15) * 32 + lhi * 8];
        #pragma unroll
        for (int i = 0; i < 2; ++i)
            #pragma unroll
            for (int j = 0; j < 2; ++j)
                acc[i][j] = __builtin_amdgcn_mfma_f32_16x16x32_bf16(af[i], bf[j], acc[i][j], 0, 0, 0);
        cur ^= 1;
    }
    #pragma unroll
    for (int i = 0; i < 2; ++i)
    #pragma unroll
    for (int j = 0; j < 2; ++j) {
        const int col = n0 + wn * 32 + j * 16 + l15;
        if (col < OUT_DIM) {
            const float bb = ob[col];
            #pragma unroll
            for (int r = 0; r < 4; ++r) {
                const int gm = wm * 32 + i * 16 + lhi * 4 + r;
                out[(size_t)(m0 + gm) * OUT_DIM + col] = acc[i][j][r] + bb;
            }
        }
    }
}

extern "C" void kernel_launch(void* const* d_in, const int* in_sizes, int n_in,
                              void* d_out, int out_size, void* d_ws, size_t ws_size,
                              hipStream_t stream) {
    const float* x      = (const float*)d_in[0];
    const float* gate_w = (const float*)d_in[2];
    const float* w1     = (const float*)d_in[3];
    const float* b1     = (const float*)d_in[4];
    const float* w2     = (const float*)d_in[5];
    const float* b2     = (const float*)d_in[6];
    const float* w3     = (const float*)d_in[7];
    const float* b3     = (const float*)d_in[8];
    const float* sw1    = (const float*)d_in[9];
    const float* sb1    = (const float*)d_in[10];
    const float* sw2    = (const float*)d_in[11];
    const float* sb2    = (const float*)d_in[12];
    const float* sw3    = (const float*)d_in[13];
    const float* sb3    = (const float*)d_in[14];
    const float* ow     = (const float*)d_in[15];
    const float* ob     = (const float*)d_in[16];
    float* out = (float*)d_out;

    char* ws = (char*)d_ws;
    size_t off = 0;
    auto alloc = [&](size_t bytes) -> void* {
        void* p = (void*)(ws + off);
        off += (bytes + 255) & ~(size_t)255;
        return p;
    };

    int*   meta   = (int*)alloc(2048);
    int*   topi   = (int*)alloc((size_t)B_TOK * 2 * 4);
    float* topw   = (float*)alloc((size_t)B_TOK * 2 * 4);
    int*   t2r    = (int*)alloc((size_t)B_TOK * 2 * 4);
    int*   glist  = (int*)alloc((size_t)(B_TOK * 2 + B_TOK) * 4);
    float* job_w  = (float*)alloc((size_t)B_TOK * 2 * 4);
    u16*   xb     = (u16*)alloc((size_t)B_TOK * W_DIM * 2);
    u16*   w1b    = (u16*)alloc((size_t)E_N * INTER * W_DIM * 2);
    u16*   w3b    = (u16*)alloc((size_t)E_N * INTER * W_DIM * 2);
    u16*   w2b    = (u16*)alloc((size_t)E_N * W_DIM * INTER * 2);
    u16*   sw1b   = (u16*)alloc((size_t)SH_INTER * W_DIM * 2);
    u16*   sw3b   = (u16*)alloc((size_t)SH_INTER * W_DIM * 2);
    u16*   sw2b   = (u16*)alloc((size_t)W_DIM * SH_INTER * 2);
    u16*   owb    = (u16*)alloc((size_t)OUT_DIM * W_DIM * 2);
    u16*   hbuf   = (u16*)alloc((size_t)B_TOK * 2 * INTER * 2);
    u16*   pbuf   = (u16*)alloc((size_t)B_TOK * SH_INTER * 2);
    float* y2     = (float*)alloc((size_t)B_TOK * 2 * W_DIM * 4);
    float* zbuf   = (float*)alloc((size_t)B_TOK * W_DIM * 4);
    u16*   ybf    = (u16*)alloc((size_t)B_TOK * W_DIM * 2);
    if (off > ws_size) return;

    dim3 blk(256);

    CastArgs ca;
    ca.s[0] = { (const float4*)x,   (uint4*)xb,   B_TOK * W_DIM / 8 };
    ca.s[1] = { (const float4*)w1,  (uint4*)w1b,  E_N * INTER * W_DIM / 8 };
    ca.s[2] = { (const float4*)w3,  (uint4*)w3b,  E_N * INTER * W_DIM / 8 };
    ca.s[3] = { (const float4*)w2,  (uint4*)w2b,  E_N * W_DIM * INTER / 8 };
    ca.s[4] = { (const float4*)sw1, (uint4*)sw1b, SH_INTER * W_DIM / 8 };
    ca.s[5] = { (const float4*)sw3, (uint4*)sw3b, SH_INTER * W_DIM / 8 };
    ca.s[6] = { (const float4*)sw2, (uint4*)sw2b, W_DIM * SH_INTER / 8 };
    ca.s[7] = { (const float4*)ow,  (uint4*)owb,  OUT_DIM * W_DIM / 8 };
    int total8 = 0;
    for (int i = 0; i < 8; ++i) total8 += ca.s[i].n8;
    cast_all<<<dim3(total8 / 2048), blk, 0, stream>>>(ca);

    gate_topk<<<dim3(B_TOK / 4), blk, 0, stream>>>(x, gate_w, topi, topw);
    route_build<<<1, blk, 0, stream>>>(topi, topw, meta, glist, job_w, t2r);

    // g1 merged: routed (<=48 jobs) + shared (16 jobs)
    g1_dual<<<dim3(64, SH_INTER / 64), blk, 0, stream>>>(
        xb, glist, meta, w1b, w3b, b1, b3, sw1b, sw3b, sb1, sb3, hbuf, pbuf);

    // g2 merged: routed (<=80 jobs) + shared (32 jobs)
    g2_gemm<<<dim3(112, W_DIM / 64), blk, 0, stream>>>(
        meta, hbuf, pbuf, w2b, b2, sw2b, sb2, job_w, y2, zbuf);

    combine_k<<<dim3(B_TOK * W_DIM / 4 / 256), blk, 0, stream>>>(y2, zbuf, t2r, ybf);

    gout<<<dim3(B_TOK / 64, 2), blk, 0, stream>>>(ybf, owb, ob, out);
}